// Round 3
// baseline (264820.630 us; speedup 1.0000x reference)
//
#include <hip/hip_runtime.h>
#include <math.h>

// hNet recurrence on MI355X — single-load-K, 25-barrier/step design.
// 64 independent per-batch-row sequential recurrences -> 64 WGs x 1024 thr,
// all 4096 steps internal, intra-WG barriers only.
//
// Per layer j, thread t owns an 8x8 block of K_j:
//   r = t>>5 (h-block 0..31), c = t&31 (i-block 0..31)
// loaded ONCE into 16 float4 regs, used for BOTH matvecs:
//   mv1: a[h] = sum_i x[i] K[h,i]   (reduce c: shfl x16,x8 + partA[h][9])
//   mv2: q[i] = sum_h z[h] K[h,i]   (reduce r: shfl x32 + partX[w][256])
//
// ws layout (floats):
//   KS[j][p][t][v]  262144 @ 0        (p: hl=p>>1, i-half=p&1)
//   WOT[f][h]        16384 @ 262144   = Wopen[h][f]
//   WCT[h][o]        16384 @ 278528   = Wclose[o][h]
// total 294912 floats = 1,179,648 bytes

#define NS 4096
#define HSTEP 0.1f
#define EPSN 1e-3f

#define KS_OFF 0
#define WOT_OFF 262144
#define WCT_OFF 278528

__global__ __launch_bounds__(256) void prep_kernel(
    const float* __restrict__ K, const float* __restrict__ Wo,
    const float* __restrict__ Wc, float* __restrict__ ws) {
  int idx = blockIdx.x * blockDim.x + threadIdx.x;
  if (idx < 262144) {
    // idx = ((j*16 + p)*1024 + t)*4 + v
    int j = idx >> 16;
    int p = (idx >> 12) & 15;
    int t = (idx >> 2) & 1023;
    int v = idx & 3;
    int r = t >> 5, cc = t & 31;
    int h = (r << 3) + (p >> 1);
    int i = (cc << 3) + ((p & 1) << 2) + v;
    ws[KS_OFF + idx] = K[(h << 10) + (i << 2) + j];  // K[h][i][j]
  }
  if (idx < 16384) {
    int f = idx >> 8, h = idx & 255;   // WOT[f][h] = Wopen[h][f]
    ws[WOT_OFF + idx] = Wo[(h << 6) + f];
    int hh = idx >> 6, o = idx & 63;   // WCT[h][o] = Wclose[o][h]
    ws[WCT_OFF + idx] = Wc[(o << 8) + hh];
  }
}

__global__ __launch_bounds__(1024) void hnet_main(
    const float* __restrict__ Frc, const float* __restrict__ ws,
    float* __restrict__ out) {
  const int b = blockIdx.x;
  const int t = threadIdx.x;
  const int w = t >> 6;      // 16 waves
  const int lane = t & 63;
  const int r = t >> 5;      // h-block 0..31
  const int c = t & 31;      // i-block 0..31

  const float4* __restrict__ WOT4 = (const float4*)(ws + WOT_OFF);
  const float* __restrict__ WCT = ws + WCT_OFF;
  const float4* __restrict__ KS4 = (const float4*)(ws + KS_OFF);
  const float* __restrict__ Fb = Frc + (size_t)b * 64 * NS;  // [f][i]
  float* __restrict__ Ob = out + (size_t)b * 64 * NS;        // [o][i]

  // x transposed: element e at xs_t[(e&7)*32 + (e>>3)] (conflict-free mv1 read)
  __shared__ float xs_t[256];
  __shared__ float zs[256];
  __shared__ float pbuf[2][256];
  __shared__ __align__(16) float partA[2304];  // mv1 partials, stride 9
  __shared__ __align__(16) float partX[4096];  // proj partials / mv2 partials
  __shared__ __align__(16) float partY[1024];  // y partials
  __shared__ double red2[8];
  __shared__ double red5[20];

  // ---- init state + P(0) = proj(F(:,0))
  if (t < 256) { xs_t[t] = 0.f; zs[t] = 0.f; }
  {
    float4 acc = {0.f, 0.f, 0.f, 0.f};
#pragma unroll
    for (int k = 0; k < 4; ++k) {
      int f = (w << 2) + k;
      float fv = Fb[(size_t)f * NS];          // wave-uniform -> 1 transaction
      float4 wv = WOT4[(f << 6) + lane];
      acc.x += fv * wv.x; acc.y += fv * wv.y;
      acc.z += fv * wv.z; acc.w += fv * wv.w;
    }
    ((float4*)partX)[(w << 6) + lane] = acc;
  }
  __syncthreads();  // B0
  if (t < 256) {
    float p0 = 0.f;
#pragma unroll
    for (int s = 0; s < 16; ++s) p0 += partX[(s << 8) + t];
    pbuf[0][t] = p0;
  }
  __syncthreads();  // B1 (partX free for loop's PROJ)

  for (int i = 0; i < NS; ++i) {
    float* __restrict__ P = pbuf[i & 1];
    float* __restrict__ Pn = pbuf[(i + 1) & 1];

    // ---- PROJ: partials of F(:,i+1) @ Wopen^T  (Fip=0 past the end)
    {
      const int ip = i + 1;
      float4 acc = {0.f, 0.f, 0.f, 0.f};
#pragma unroll
      for (int k = 0; k < 4; ++k) {
        int f = (w << 2) + k;
        float fv = (ip < NS) ? Fb[(size_t)f * NS + ip] : 0.f;
        float4 wv = WOT4[(f << 6) + lane];
        acc.x += fv * wv.x; acc.y += fv * wv.y;
        acc.z += fv * wv.z; acc.w += fv * wv.w;
      }
      ((float4*)partX)[(w << 6) + lane] = acc;
    }
    __syncthreads();  // S2

    // ---- PN (waves 0-3): Pn assemble + 5-moment reduce; overlaps layer-0 mv1
    if (t < 256) {
      float pn = 0.f;
#pragma unroll
      for (int s = 0; s < 16; ++s) pn += partX[(s << 8) + t];
      Pn[t] = pn;
      float pv = P[t];
      double v0 = pv, v1 = pn;
      double v2 = (double)pv * pv, v3 = (double)pv * pn, v4 = (double)pn * pn;
#pragma unroll
      for (int off = 1; off < 64; off <<= 1) {
        v0 += __shfl_xor(v0, off); v1 += __shfl_xor(v1, off);
        v2 += __shfl_xor(v2, off); v3 += __shfl_xor(v3, off);
        v4 += __shfl_xor(v4, off);
      }
      if (lane == 0) {
        red5[w * 5 + 0] = v0; red5[w * 5 + 1] = v1; red5[w * 5 + 2] = v2;
        red5[w * 5 + 3] = v3; red5[w * 5 + 4] = v4;
      }
    }
    // NOTE: no barrier here — layer-0's L1 fences red5/Pn before any consumer.

    float mFv[4], invFv[4];  // per-layer force-norm stats (filled at j==0)
    float cf = 1.f, df = 0.f;
#pragma unroll
    for (int j = 0; j < 4; ++j) {
      cf = cf * (float)(4 - j) * 0.25f;
      df = (df * (float)(4 - j) + (float)j) * 0.25f;

      // ---- load thread's 8x8 K_j block (serves mv1 AND mv2)
      float4 kreg[16];
      {
        const float4* kp = KS4 + ((size_t)(j << 4) << 10) + t;
#pragma unroll
        for (int p = 0; p < 16; ++p) kreg[p] = kp[(size_t)p << 10];
      }

      // ---- mv1: a[h] = sum_i x[i] K[h,i]
      float xv[8];
#pragma unroll
      for (int v = 0; v < 8; ++v) xv[v] = xs_t[(v << 5) + c];
      float pa[8];
#pragma unroll
      for (int hl = 0; hl < 8; ++hl) {
        float4 k0 = kreg[hl * 2], k1 = kreg[hl * 2 + 1];
        pa[hl] = xv[0] * k0.x + xv[1] * k0.y + xv[2] * k0.z + xv[3] * k0.w +
                 xv[4] * k1.x + xv[5] * k1.y + xv[6] * k1.z + xv[7] * k1.w;
      }
#pragma unroll
      for (int hl = 0; hl < 8; ++hl) {
        pa[hl] += __shfl_xor(pa[hl], 16);
        pa[hl] += __shfl_xor(pa[hl], 8);
      }
      if (c < 8) {
#pragma unroll
        for (int hl = 0; hl < 8; ++hl) partA[((r << 3) + hl) * 9 + c] = pa[hl];
      }
      __syncthreads();  // L1 (also fences red5/Pn writes from PN phase)

      float a = 0.f;
      if (t < 256) {
        const float* pp = partA + t * 9;
#pragma unroll
        for (int g = 0; g < 8; ++g) a += pp[g];
        double s1 = a, s2 = (double)a * a;
#pragma unroll
        for (int off = 1; off < 64; off <<= 1) {
          s1 += __shfl_xor(s1, off); s2 += __shfl_xor(s2, off);
        }
        if (lane == 0) { red2[w * 2] = s1; red2[w * 2 + 1] = s2; }
      }
      __syncthreads();  // L2

      if (t < 256) {
        if (j == 0) {
          // all four layers' force-norm stats from the 5 moments, once
          const double sP = red5[0] + red5[5] + red5[10] + red5[15];
          const double sPn = red5[1] + red5[6] + red5[11] + red5[16];
          const double dPP = red5[2] + red5[7] + red5[12] + red5[17];
          const double dPPn = red5[3] + red5[8] + red5[13] + red5[18];
          const double dPnn = red5[4] + red5[9] + red5[14] + red5[19];
          float cj = 1.f, dj = 0.f;
#pragma unroll
          for (int jj = 0; jj < 4; ++jj) {
            cj = cj * (float)(4 - jj) * 0.25f;
            dj = (dj * (float)(4 - jj) + (float)jj) * 0.25f;
            double mFd = ((double)cj * sP + (double)dj * sPn) * (1.0 / 256.0);
            double raw2 = (double)cj * cj * dPP +
                          2.0 * (double)cj * dj * dPPn + (double)dj * dj * dPnn;
            mFv[jj] = (float)mFd;
            invFv[jj] =
                1.0f / sqrtf((float)(raw2 - 256.0 * mFd * mFd) + EPSN);
          }
        }
        double sumA = red2[0] + red2[2] + red2[4] + red2[6];
        double ssA = red2[1] + red2[3] + red2[5] + red2[7];
        float mA = (float)(sumA * (1.0 / 256.0));
        float cssA = (float)(ssA - sumA * sumA * (1.0 / 256.0));
        float invA = 1.0f / sqrtf(cssA + EPSN);
        float aj = fmaxf((a - mA) * invA, 0.f);
        float fiv = cf * P[t] + df * Pn[t];
        float fi = fmaxf((fiv - mFv[j]) * invFv[j], 0.f);
        zs[t] += HSTEP * (aj + fi);
      }
      __syncthreads();  // L3 (zs complete)

      // ---- mv2: q[i] = sum_h z[h] K[h,i]  (kreg reused); j==3: + y partials
      float pq[8];
#pragma unroll
      for (int v = 0; v < 8; ++v) pq[v] = 0.f;
#pragma unroll
      for (int hl = 0; hl < 8; ++hl) {
        float zv = zs[(r << 3) + hl];  // 2 addrs/wave -> broadcast
        float4 k0 = kreg[hl * 2], k1 = kreg[hl * 2 + 1];
        pq[0] += zv * k0.x; pq[1] += zv * k0.y;
        pq[2] += zv * k0.z; pq[3] += zv * k0.w;
        pq[4] += zv * k1.x; pq[5] += zv * k1.y;
        pq[6] += zv * k1.z; pq[7] += zv * k1.w;
      }
#pragma unroll
      for (int v = 0; v < 8; ++v) pq[v] += __shfl_xor(pq[v], 32);
      if (lane < 32) {
        float4 q0 = {pq[0], pq[1], pq[2], pq[3]};
        float4 q1 = {pq[4], pq[5], pq[6], pq[7]};
        float4* dst = (float4*)(partX + (w << 8) + (c << 3));
        dst[0] = q0; dst[1] = q1;
      }
      if (j == 3) {  // y partials: z final for this step after L3
        float acc = 0.f;
#pragma unroll
        for (int k = 0; k < 16; ++k) {
          int hh = (w << 4) + k;
          acc += zs[hh] * WCT[(hh << 6) + lane];
        }
        partY[(w << 6) + lane] = acc;
      }
      __syncthreads();  // L4

      float q = 0.f;
      if (t < 256) {
#pragma unroll
        for (int g = 0; g < 16; ++g) q += partX[(g << 8) + t];
        double s1 = q, s2 = (double)q * q;
#pragma unroll
        for (int off = 1; off < 64; off <<= 1) {
          s1 += __shfl_xor(s1, off); s2 += __shfl_xor(s2, off);
        }
        if (lane == 0) { red2[w * 2] = s1; red2[w * 2 + 1] = s2; }
      }
      if (j == 3 && t < 64) {  // overlapped y assemble + store
        float y = 0.f;
#pragma unroll
        for (int s = 0; s < 16; ++s) y += partY[(s << 6) + t];
        Ob[(size_t)t * NS + i] = y;
      }
      __syncthreads();  // L5

      if (t < 256) {
        double sumQ = red2[0] + red2[2] + red2[4] + red2[6];
        double ssQ = red2[1] + red2[3] + red2[5] + red2[7];
        float mQ = (float)(sumQ * (1.0 / 256.0));
        float cssQ = (float)(ssQ - sumQ * sumQ * (1.0 / 256.0));
        float invQ = 1.0f / sqrtf(cssQ + EPSN);
        int loc = ((t & 7) << 5) + (t >> 3);  // transposed slot for elem t
        xs_t[loc] -= HSTEP * fmaxf((q - mQ) * invQ, 0.f);
      }
      __syncthreads();  // L6 (xs complete)
    }
  }
}

extern "C" void kernel_launch(void* const* d_in, const int* in_sizes, int n_in,
                              void* d_out, int out_size, void* d_ws,
                              size_t ws_size, hipStream_t stream) {
  const float* Frc = (const float*)d_in[0];    // [64, 64, 4096]
  const float* K = (const float*)d_in[1];      // [256, 256, 4]
  const float* Wopen = (const float*)d_in[2];  // [256, 64]
  const float* Wclose = (const float*)d_in[3]; // [64, 256]
  float* out = (float*)d_out;                  // [64, 64, 4096]
  float* ws = (float*)d_ws;                    // >= 1,179,648 bytes

  prep_kernel<<<1024, 256, 0, stream>>>(K, Wopen, Wclose, ws);
  hnet_main<<<64, 1024, 0, stream>>>(Frc, ws, out);
}